// Round 4
// baseline (858.103 us; speedup 1.0000x reference)
//
#include <hip/hip_runtime.h>
#include <hip/hip_bf16.h>
#include <stdint.h>

#define FLEN 4096
#define TLEN 512
#define NB   4
#define NH   8

typedef __attribute__((ext_vector_type(8))) short short8;
typedef __attribute__((ext_vector_type(4))) float floatx4;
typedef unsigned short ushort_t;
typedef unsigned int uint_t;

typedef __attribute__((address_space(1))) const void gconst_as;
typedef __attribute__((address_space(3))) void lds_as;

__device__ inline ushort_t f2bf(float f) {
    union { float f; uint_t u; } v; v.f = f;
    uint_t r = (v.u + 0x7FFFu + ((v.u >> 16) & 1u)) >> 16;
    return (ushort_t)r;
}
__device__ inline float bf2f(uint_t u) {
    union { uint_t u; float f; } v; v.u = u << 16;
    return v.f;
}
__device__ inline short8 pack_bf16(floatx4 a, floatx4 b) {
    short8 r;
    r[0]=(short)f2bf(a[0]); r[1]=(short)f2bf(a[1]); r[2]=(short)f2bf(a[2]); r[3]=(short)f2bf(a[3]);
    r[4]=(short)f2bf(b[0]); r[5]=(short)f2bf(b[1]); r[6]=(short)f2bf(b[2]); r[7]=(short)f2bf(b[3]);
    return r;
}

// ---- fp32 -> bf16 + fused per-row LN stats (for `from`) ----
__global__ __launch_bounds__(256) void conv_from_stats(const float* __restrict__ X,
                                                       ushort_t* __restrict__ Xb,
                                                       float* __restrict__ S) {
    int w = threadIdx.x >> 6, l = threadIdx.x & 63;
    int row = blockIdx.x * 4 + w;
    const float* xr = X + (size_t)row * 512;
    floatx4 v0 = *(const floatx4*)(xr + l * 8);
    floatx4 v1 = *(const floatx4*)(xr + l * 8 + 4);
    *(short8*)(Xb + (size_t)row * 512 + l * 8) = pack_bf16(v0, v1);
    float s = 0.f, q = 0.f;
    #pragma unroll
    for (int j = 0; j < 4; ++j) { s += v0[j] + v1[j]; q += v0[j]*v0[j] + v1[j]*v1[j]; }
    #pragma unroll
    for (int off = 1; off < 64; off <<= 1) { s += __shfl_xor(s, off); q += __shfl_xor(q, off); }
    if (l == 0) {
        float mu = s * (1.f / 512.f);
        float var = q * (1.f / 512.f) - mu * mu;
        S[row * 2] = mu;
        S[row * 2 + 1] = rsqrtf(var + 1e-5f);
    }
}

// ---- to / fpos / tpos -> bf16, one launch ----
// n8: to=131072, fpos=262144, tpos=32768 -> blocks 512 + 1024 + 128 = 1664
__global__ void conv3(const float* __restrict__ to, ushort_t* __restrict__ tob,
                      const float* __restrict__ fpos, ushort_t* __restrict__ fposb,
                      const float* __restrict__ tpos, ushort_t* __restrict__ tposb) {
    int bid = blockIdx.x;
    const float* src; ushort_t* dst; int i;
    if (bid < 512)       { src = to;   dst = tob;   i = bid * 256 + threadIdx.x; }
    else if (bid < 1536) { src = fpos; dst = fposb; i = (bid - 512) * 256 + threadIdx.x; }
    else                 { src = tpos; dst = tposb; i = (bid - 1536) * 256 + threadIdx.x; }
    floatx4 v0 = *(const floatx4*)(src + (size_t)i * 8);
    floatx4 v1 = *(const floatx4*)(src + (size_t)i * 8 + 4);
    *(short8*)(dst + (size_t)i * 8) = pack_bf16(v0, v1);
}

// ---- 6 weight transposes (fp32 [in][out] -> bf16 [out][in'] with stride/col-offset) ----
struct T6Args {
    const float* s[6];
    ushort_t* d[6];
    int stride[6];
    int coff[6];
};
__global__ __launch_bounds__(256) void transpose6(T6Args a) {
    int m = blockIdx.x >> 6;
    int bx = blockIdx.x & 7, by = (blockIdx.x >> 3) & 7;
    __shared__ float tile[64][65];
    int rb = by * 64, cb = bx * 64;
    int tr = threadIdx.x >> 6, tc = threadIdx.x & 63;
    const float* src = a.s[m];
    #pragma unroll
    for (int i = 0; i < 16; ++i) {
        int rr = tr + i * 4;
        tile[rr][tc] = src[(size_t)(rb + rr) * 512 + cb + tc];
    }
    __syncthreads();
    ushort_t* dst = a.d[m];
    int stride = a.stride[m], coff = a.coff[m];
    #pragma unroll
    for (int i = 0; i < 16; ++i) {
        int rr = tr + i * 4;
        dst[(size_t)(cb + rr) * stride + coff + rb + tc] = f2bf(tile[tc][rr]);
    }
}

// ---- biases + gate weight concat/transpose prep (grid 64x256 = 16384) ----
__global__ void prep(const float* bq, const float* bfp, const float* bk, const float* btp,
                     const float* bgF, const float* bgpF, const float* bgT, const float* bgpT,
                     const float* WgF, const float* WgpF, const float* WgT_, const float* WgpT,
                     float* bqf, float* bkt, float* bgFc, float* bgTc,
                     ushort_t* WgFT, ushort_t* WgTT) {
    int i = blockIdx.x * 256 + threadIdx.x;
    if (i < 512) { bqf[i] = bq[i] + bfp[i]; bkt[i] = bk[i] + btp[i]; }
    if (i < 8) { bgFc[i] = bgF[i] + bgpF[i] + 1.0f; bgTc[i] = bgT[i] + bgpT[i]; }
    int j = i >> 10, k = i & 1023;
    float vF = 0.f, vT = 0.f;
    if (j < 8) {
        vF = (k < 512) ? WgF[k * 8 + j] : WgpF[(k - 512) * 8 + j];
        vT = (k < 512) ? WgT_[k * 8 + j] : WgpT[(k - 512) * 8 + j];
    }
    WgFT[i] = f2bf(vF);
    WgTT[i] = f2bf(vT);
}

// ---- tiled bf16 GEMM: A=[A1|A2(mod)] [M,K] x WT[512][K] -> 128x128 tile, BK=64 ----
// LDS XOR-swizzle (elem col ^ (row&7)*8) via pre-swizzled global source.
// epi 0: Cb = bf16(acc + bias[c])
// epi 2: permuted-V layout
// epi 3: Cf = (f2 - mu)*rstd * (acc + bias[c] + 1)
__global__ __launch_bounds__(256, 3) void gemm_bf16(
    const ushort_t* __restrict__ A1, const ushort_t* __restrict__ A2, int rm, int K,
    const ushort_t* __restrict__ WT, const float* __restrict__ bias,
    float* __restrict__ Cf, ushort_t* __restrict__ Cb,
    const float* __restrict__ f2, const float* __restrict__ stats, int epi)
{
    __shared__ ushort_t As[128 * 64];
    __shared__ ushort_t Bs[128 * 64];
    int tid = threadIdx.x;
    int w = tid >> 6, l = tid & 63, fr = l & 15, g = l >> 4;
    int wr = w >> 1, wc = w & 1;
    int rb = blockIdx.x * 128, cb = blockIdx.y * 128;

    floatx4 acc[4][4];
    #pragma unroll
    for (int mt = 0; mt < 4; ++mt)
        #pragma unroll
        for (int nt = 0; nt < 4; ++nt)
            #pragma unroll
            for (int i = 0; i < 4; ++i) acc[mt][nt][i] = 0.f;

    int srow = w * 8 + (l >> 3);                 // 0..31
    int scx = ((l & 7) ^ (l >> 3)) * 8;          // swizzled k-offset 0..56

    for (int kb = 0; kb < K; kb += 64) {
        #pragma unroll
        for (int i = 0; i < 4; ++i) {
            int ra = rb + i * 32 + srow;
            int ka = kb + scx;
            const ushort_t* ga = (ka < 512) ? (A1 + (size_t)ra * 512 + ka)
                                            : (A2 + (size_t)(ra & rm) * 512 + (ka - 512));
            __builtin_amdgcn_global_load_lds((gconst_as*)ga, (lds_as*)(As + i * 2048 + w * 512), 16, 0, 0);
            const ushort_t* gb = WT + (size_t)(cb + i * 32 + srow) * K + kb + scx;
            __builtin_amdgcn_global_load_lds((gconst_as*)gb, (lds_as*)(Bs + i * 2048 + w * 512), 16, 0, 0);
        }
        __syncthreads();
        #pragma unroll
        for (int kk = 0; kk < 2; ++kk) {
            int co = (kk * 32 + g * 8) ^ ((fr & 7) * 8);
            short8 af[4], bw[4];
            #pragma unroll
            for (int mt = 0; mt < 4; ++mt)
                af[mt] = *(const short8*)&As[(wr * 64 + mt * 16 + fr) * 64 + co];
            #pragma unroll
            for (int nt = 0; nt < 4; ++nt)
                bw[nt] = *(const short8*)&Bs[(wc * 64 + nt * 16 + fr) * 64 + co];
            #pragma unroll
            for (int mt = 0; mt < 4; ++mt)
                #pragma unroll
                for (int nt = 0; nt < 4; ++nt)
                    acc[mt][nt] = __builtin_amdgcn_mfma_f32_16x16x32_bf16(af[mt], bw[nt], acc[mt][nt], 0, 0, 0);
        }
        __syncthreads();
    }

    #pragma unroll
    for (int mt = 0; mt < 4; ++mt) {
        #pragma unroll
        for (int nt = 0; nt < 4; ++nt) {
            #pragma unroll
            for (int i = 0; i < 4; ++i) {
                int r = rb + wr * 64 + mt * 16 + g * 4 + i;
                int c = cb + wc * 64 + nt * 16 + fr;
                float v = acc[mt][nt][i];
                if (epi == 0) {
                    Cb[(size_t)r * 512 + c] = f2bf(v + bias[c]);
                } else if (epi == 2) {
                    int bb = r >> 9, t = r & 511, hh = c >> 6, d = c & 63;
                    size_t idx = ((size_t)((bb * 8 + hh) * 64 + d)) * 512 +
                                 (t & ~31) + ((t >> 2) & 3) * 8 + ((t >> 4) & 1) * 4 + (t & 3);
                    Cb[idx] = f2bf(v + bias[c]);
                } else {
                    float mu = stats[r * 2], rs = stats[r * 2 + 1];
                    Cf[(size_t)r * 512 + c] = (f2[(size_t)r * 512 + c] - mu) * rs * (v + bias[c] + 1.0f);
                }
            }
        }
    }
}

// ---- gate via MFMA: sigmoid([X|P] @ WgT^T + bgc) ; N=16 tile (cols 8..15 zero) ----
// layout 0: G[row*8+j]   layout 1: G[((row>>9)*8+j)*512 + (row&511)]
__global__ __launch_bounds__(256) void gate_mfma(
    const ushort_t* __restrict__ A1, const ushort_t* __restrict__ A2, int rm,
    const ushort_t* __restrict__ WgT, const float* __restrict__ bgc,
    float* __restrict__ G, int layout)
{
    int tid = threadIdx.x, w = tid >> 6, l = tid & 63;
    int fr = l & 15, g = l >> 4;
    int rb = blockIdx.x * 64 + w * 16;
    int arow = rb + fr;
    floatx4 acc = {0.f, 0.f, 0.f, 0.f};
    #pragma unroll
    for (int ks = 0; ks < 32; ++ks) {
        int k0 = ks * 32 + g * 8;
        const ushort_t* ap = (k0 < 512) ? (A1 + (size_t)arow * 512 + k0)
                                        : (A2 + (size_t)(arow & rm) * 512 + (k0 - 512));
        short8 af = *(const short8*)ap;
        short8 bw = *(const short8*)(WgT + (size_t)fr * 1024 + k0);
        acc = __builtin_amdgcn_mfma_f32_16x16x32_bf16(af, bw, acc, 0, 0, 0);
    }
    if (fr < 8) {
        #pragma unroll
        for (int i = 0; i < 4; ++i) {
            int r = rb + g * 4 + i;
            float z = acc[i] + bgc[fr];
            float gv = 1.f / (1.f + __expf(-z));
            if (layout == 0) G[(size_t)r * 8 + fr] = gv;
            else G[((size_t)((r >> 9) * 8 + fr)) * 512 + (r & 511)] = gv;
        }
    }
}

// ---- fused attention: swapped QK^T, P in registers, LDS-staged coalesced probs ----
__global__ __launch_bounds__(256, 4) void attn_kernel(
    const ushort_t* __restrict__ Q, const ushort_t* __restrict__ K,
    const ushort_t* __restrict__ Vp,
    const float* __restrict__ g_from, const float* __restrict__ gToT,
    float* __restrict__ probs, ushort_t* __restrict__ ctrl)
{
    __shared__ float chunkbuf[4][16 * 132];   // per-wave staging (padded rows)
    int tid = threadIdx.x, w = tid >> 6, l = tid & 63;
    int fr = l & 15, g = l >> 4;
    int bh = blockIdx.y, b = bh >> 3, h = bh & 7;
    int fb = blockIdx.x * 64 + w * 16;
    int f = fb + fr;

    const ushort_t* qp = Q + ((size_t)(b * FLEN) + f) * 512 + h * 64 + g * 8;
    short8 qf0 = *(const short8*)qp;
    short8 qf1 = *(const short8*)(qp + 32);

    uint_t pbx[32], pby[32];
    float ssum = 0.f;
    const float* gtp = gToT + (size_t)bh * 512;

    #pragma unroll
    for (int tt = 0; tt < 32; ++tt) {
        const ushort_t* kp = K + ((size_t)(b * TLEN) + tt * 16 + fr) * 512 + h * 64 + g * 8;
        short8 kf0 = *(const short8*)kp;
        short8 kf1 = *(const short8*)(kp + 32);
        floatx4 sc = {0.f, 0.f, 0.f, 0.f};
        sc = __builtin_amdgcn_mfma_f32_16x16x32_bf16(kf0, qf0, sc, 0, 0, 0);  // C[t][f]
        sc = __builtin_amdgcn_mfma_f32_16x16x32_bf16(kf1, qf1, sc, 0, 0, 0);
        floatx4 gt = *(const floatx4*)(gtp + tt * 16 + g * 4);
        float e0 = __expf(sc[0] * 0.125f), e1 = __expf(sc[1] * 0.125f);
        float e2 = __expf(sc[2] * 0.125f), e3 = __expf(sc[3] * 0.125f);
        ssum += e0 + e1 + e2 + e3;
        float p0 = e0 * gt[0], p1 = e1 * gt[1], p2 = e2 * gt[2], p3 = e3 * gt[3];
        pbx[tt] = (uint_t)f2bf(p0) | ((uint_t)f2bf(p1) << 16);
        pby[tt] = (uint_t)f2bf(p2) | ((uint_t)f2bf(p3) << 16);
    }
    ssum += __shfl_xor(ssum, 16);
    ssum += __shfl_xor(ssum, 32);
    float fac = g_from[((size_t)(b * FLEN) + f) * 8 + h] / ssum;

    // PV: control^T[d][f] = sum_t V^T[d][t] * P^T[t][f]
    floatx4 oacc[4];
    #pragma unroll
    for (int dt = 0; dt < 4; ++dt)
        #pragma unroll
        for (int i = 0; i < 4; ++i) oacc[dt][i] = 0.f;

    #pragma unroll
    for (int kt = 0; kt < 16; ++kt) {
        union { uint_t u[4]; short8 v; } bu;
        bu.u[0] = pbx[2 * kt];     bu.u[1] = pby[2 * kt];
        bu.u[2] = pbx[2 * kt + 1]; bu.u[3] = pby[2 * kt + 1];
        #pragma unroll
        for (int dt = 0; dt < 4; ++dt) {
            const ushort_t* vp = Vp + ((size_t)(bh * 64) + dt * 16 + fr) * 512 + kt * 32 + g * 8;
            short8 vf = *(const short8*)vp;
            oacc[dt] = __builtin_amdgcn_mfma_f32_16x16x32_bf16(vf, bu.v, oacc[dt], 0, 0, 0);
        }
    }

    // probs: per-wave LDS transpose chunks -> 128-B-contiguous per-lane stores
    float* cbuf = chunkbuf[w];
    int fl = l >> 2, seg = l & 3;
    #pragma unroll
    for (int c = 0; c < 4; ++c) {
        #pragma unroll
        for (int t8 = 0; t8 < 8; ++t8) {
            int tt = c * 8 + t8;
            floatx4 pv;
            pv[0] = bf2f(pbx[tt] & 0xffffu) * fac;
            pv[1] = bf2f(pbx[tt] >> 16) * fac;
            pv[2] = bf2f(pby[tt] & 0xffffu) * fac;
            pv[3] = bf2f(pby[tt] >> 16) * fac;
            *(floatx4*)&cbuf[fr * 132 + t8 * 16 + g * 4] = pv;
        }
        const float* srcp = &cbuf[fl * 132 + seg * 32];
        float* gdst = probs + ((size_t)bh * FLEN + fb + fl) * 512 + c * 128 + seg * 32;
        #pragma unroll
        for (int m8 = 0; m8 < 8; ++m8)
            *(floatx4*)(gdst + m8 * 4) = *(const floatx4*)(srcp + m8 * 4);
    }

    // control^T -> LDS (reuse chunk region) -> coalesced bf16 control rows
    ushort_t* ctile = (ushort_t*)cbuf;           // [16][72]
    #pragma unroll
    for (int dt = 0; dt < 4; ++dt)
        #pragma unroll
        for (int i = 0; i < 4; ++i)
            ctile[fr * 72 + dt * 16 + g * 4 + i] = f2bf(oacc[dt][i] * fac);

    int dp = (l & 3) * 16;
    uint4 c0 = *(const uint4*)&ctile[fl * 72 + dp];
    uint4 c1 = *(const uint4*)&ctile[fl * 72 + dp + 8];
    ushort_t* cdst = ctrl + ((size_t)(b * FLEN) + fb + fl) * 512 + h * 64 + dp;
    *(uint4*)cdst = c0;
    *(uint4*)(cdst + 8) = c1;
}

extern "C" void kernel_launch(void* const* d_in, const int* in_sizes, int n_in,
                              void* d_out, int out_size, void* d_ws, size_t ws_size,
                              hipStream_t stream) {
    const float* from = (const float*)d_in[0];
    const float* to   = (const float*)d_in[1];
    const float* fpos = (const float*)d_in[2];
    const float* tpos = (const float*)d_in[3];
    const float* Wq  = (const float*)d_in[4];  const float* bq  = (const float*)d_in[5];
    const float* Wk  = (const float*)d_in[6];  const float* bk  = (const float*)d_in[7];
    const float* Wv  = (const float*)d_in[8];  const float* bv  = (const float*)d_in[9];
    const float* Wfp = (const float*)d_in[10]; const float* bfp = (const float*)d_in[11];
    const float* Wtp = (const float*)d_in[12]; const float* btp = (const float*)d_in[13];
    const float* Wg_to   = (const float*)d_in[14]; const float* bg_to   = (const float*)d_in[15];
    const float* Wgp_to  = (const float*)d_in[16]; const float* bgp_to  = (const float*)d_in[17];
    const float* Wg_from = (const float*)d_in[18]; const float* bg_from = (const float*)d_in[19];
    const float* Wgp_from= (const float*)d_in[20]; const float* bgp_from= (const float*)d_in[21];
    const float* Wm  = (const float*)d_in[22]; const float* bm  = (const float*)d_in[23];

    char* ws = (char*)d_ws;
    ushort_t* WqfT = (ushort_t*)ws; ws += 512 * 1024 * 2;
    ushort_t* WktT = (ushort_t*)ws; ws += 512 * 1024 * 2;
    ushort_t* WvT  = (ushort_t*)ws; ws += 512 * 512 * 2;
    ushort_t* WmT  = (ushort_t*)ws; ws += 512 * 512 * 2;
    ushort_t* WgFT = (ushort_t*)ws; ws += 16 * 1024 * 2;
    ushort_t* WgTT = (ushort_t*)ws; ws += 16 * 1024 * 2;
    float* bqf  = (float*)ws; ws += 512 * 4;
    float* bkt  = (float*)ws; ws += 512 * 4;
    float* bgFc = (float*)ws; ws += 64 * 4;
    float* bgTc = (float*)ws; ws += 64 * 4;
    ushort_t* fbf = (ushort_t*)ws; ws += (size_t)NB * FLEN * 512 * 2;
    ushort_t* tbf = (ushort_t*)ws; ws += (size_t)NB * TLEN * 512 * 2;
    ushort_t* Qbf = (ushort_t*)ws; ws += (size_t)NB * FLEN * 512 * 2;
    ushort_t* Kbf = (ushort_t*)ws; ws += (size_t)NB * TLEN * 512 * 2;
    ushort_t* Vp  = (ushort_t*)ws; ws += (size_t)NB * NH * 64 * 512 * 2;
    float* gFrom = (float*)ws; ws += (size_t)NB * FLEN * 8 * 4;
    float* gToT  = (float*)ws; ws += (size_t)NB * NH * 512 * 4;
    ushort_t* ctrl = (ushort_t*)ws; ws += (size_t)NB * FLEN * 512 * 2;
    float* stats = (float*)ws; ws += (size_t)NB * FLEN * 2 * 4;
    if (ws_size < (size_t)(ws - (char*)d_ws)) return;
    // pos bf16 staging aliases ctrl (ctrl written only by attn, later)
    ushort_t* fposbf = ctrl;                       // 4096*512
    ushort_t* tposbf = ctrl + (size_t)FLEN * 512;  // 512*512

    conv_from_stats<<<NB * FLEN / 4, 256, 0, stream>>>(from, fbf, stats);
    conv3<<<1664, 256, 0, stream>>>(to, tbf, fpos, fposbf, tpos, tposbf);

    T6Args ta;
    ta.s[0] = Wq;  ta.d[0] = WqfT; ta.stride[0] = 1024; ta.coff[0] = 0;
    ta.s[1] = Wfp; ta.d[1] = WqfT; ta.stride[1] = 1024; ta.coff[1] = 512;
    ta.s[2] = Wk;  ta.d[2] = WktT; ta.stride[2] = 1024; ta.coff[2] = 0;
    ta.s[3] = Wtp; ta.d[3] = WktT; ta.stride[3] = 1024; ta.coff[3] = 512;
    ta.s[4] = Wv;  ta.d[4] = WvT;  ta.stride[4] = 512;  ta.coff[4] = 0;
    ta.s[5] = Wm;  ta.d[5] = WmT;  ta.stride[5] = 512;  ta.coff[5] = 0;
    transpose6<<<384, 256, 0, stream>>>(ta);

    prep<<<64, 256, 0, stream>>>(bq, bfp, bk, btp,
                                 bg_from, bgp_from, bg_to, bgp_to,
                                 Wg_from, Wgp_from, Wg_to, Wgp_to,
                                 bqf, bkt, bgFc, bgTc, WgFT, WgTT);

    // Q = [from|fpos] @ WqfT^T + bqf ; K = [to|tpos] @ WktT^T + bkt ; V = to @ WvT^T + bv (permuted)
    gemm_bf16<<<dim3(NB * FLEN / 128, 4), 256, 0, stream>>>(fbf, fposbf, FLEN - 1, 1024, WqfT, bqf, nullptr, Qbf, nullptr, nullptr, 0);
    gemm_bf16<<<dim3(NB * TLEN / 128, 4), 256, 0, stream>>>(tbf, tposbf, TLEN - 1, 1024, WktT, bkt, nullptr, Kbf, nullptr, nullptr, 0);
    gemm_bf16<<<dim3(NB * TLEN / 128, 4), 256, 0, stream>>>(tbf, tbf, TLEN - 1, 512, WvT, bv, nullptr, Vp, nullptr, nullptr, 2);

    gate_mfma<<<NB * FLEN / 64, 256, 0, stream>>>(fbf, fposbf, FLEN - 1, WgFT, bgFc, gFrom, 0);
    gate_mfma<<<NB * TLEN / 64, 256, 0, stream>>>(tbf, tposbf, TLEN - 1, WgTT, bgTc, gToT, 1);

    float* out = (float*)d_out;
    attn_kernel<<<dim3(FLEN / 64, NB * NH), 256, 0, stream>>>(Qbf, Kbf, Vp, gFrom, gToT,
                                                              out + (size_t)NB * FLEN * 512, ctrl);

    gemm_bf16<<<dim3(NB * FLEN / 128, 4), 256, 0, stream>>>(ctrl, ctrl, FLEN - 1, 512, WmT, bm, out, nullptr, from, stats, 3);
}

// Round 5
// 627.564 us; speedup vs baseline: 1.3674x; 1.3674x over previous
//
#include <hip/hip_runtime.h>
#include <hip/hip_bf16.h>
#include <stdint.h>

#define FLEN 4096
#define TLEN 512
#define NB   4
#define NH   8

typedef __attribute__((ext_vector_type(8))) short short8;
typedef __attribute__((ext_vector_type(4))) float floatx4;
typedef unsigned short ushort_t;
typedef unsigned int uint_t;

typedef __attribute__((address_space(1))) const void gconst_as;
typedef __attribute__((address_space(3))) void lds_as;

__device__ inline ushort_t f2bf(float f) {
    union { float f; uint_t u; } v; v.f = f;
    uint_t r = (v.u + 0x7FFFu + ((v.u >> 16) & 1u)) >> 16;
    return (ushort_t)r;
}
__device__ inline float bf2f(uint_t u) {
    union { uint_t u; float f; } v; v.u = u << 16;
    return v.f;
}
__device__ inline short8 pack_bf16(floatx4 a, floatx4 b) {
    short8 r;
    r[0]=(short)f2bf(a[0]); r[1]=(short)f2bf(a[1]); r[2]=(short)f2bf(a[2]); r[3]=(short)f2bf(a[3]);
    r[4]=(short)f2bf(b[0]); r[5]=(short)f2bf(b[1]); r[6]=(short)f2bf(b[2]); r[7]=(short)f2bf(b[3]);
    return r;
}

// ---- fp32 -> bf16 + fused per-row LN stats (for `from`) ----
__global__ __launch_bounds__(256) void conv_from_stats(const float* __restrict__ X,
                                                       ushort_t* __restrict__ Xb,
                                                       float* __restrict__ S) {
    int w = threadIdx.x >> 6, l = threadIdx.x & 63;
    int row = blockIdx.x * 4 + w;
    const float* xr = X + (size_t)row * 512;
    floatx4 v0 = *(const floatx4*)(xr + l * 8);
    floatx4 v1 = *(const floatx4*)(xr + l * 8 + 4);
    *(short8*)(Xb + (size_t)row * 512 + l * 8) = pack_bf16(v0, v1);
    float s = 0.f, q = 0.f;
    #pragma unroll
    for (int j = 0; j < 4; ++j) { s += v0[j] + v1[j]; q += v0[j]*v0[j] + v1[j]*v1[j]; }
    #pragma unroll
    for (int off = 1; off < 64; off <<= 1) { s += __shfl_xor(s, off); q += __shfl_xor(q, off); }
    if (l == 0) {
        float mu = s * (1.f / 512.f);
        float var = q * (1.f / 512.f) - mu * mu;
        S[row * 2] = mu;
        S[row * 2 + 1] = rsqrtf(var + 1e-5f);
    }
}

// ---- to / fpos / tpos -> bf16, one launch ----
__global__ void conv3(const float* __restrict__ to, ushort_t* __restrict__ tob,
                      const float* __restrict__ fpos, ushort_t* __restrict__ fposb,
                      const float* __restrict__ tpos, ushort_t* __restrict__ tposb) {
    int bid = blockIdx.x;
    const float* src; ushort_t* dst; int i;
    if (bid < 512)       { src = to;   dst = tob;   i = bid * 256 + threadIdx.x; }
    else if (bid < 1536) { src = fpos; dst = fposb; i = (bid - 512) * 256 + threadIdx.x; }
    else                 { src = tpos; dst = tposb; i = (bid - 1536) * 256 + threadIdx.x; }
    floatx4 v0 = *(const floatx4*)(src + (size_t)i * 8);
    floatx4 v1 = *(const floatx4*)(src + (size_t)i * 8 + 4);
    *(short8*)(dst + (size_t)i * 8) = pack_bf16(v0, v1);
}

// ---- 6 weight transposes (fp32 [in][out] -> bf16 [out][in'] with stride/col-offset) ----
struct T6Args {
    const float* s[6];
    ushort_t* d[6];
    int stride[6];
    int coff[6];
};
__global__ __launch_bounds__(256) void transpose6(T6Args a) {
    int m = blockIdx.x >> 6;
    int bx = blockIdx.x & 7, by = (blockIdx.x >> 3) & 7;
    __shared__ float tile[64][65];
    int rb = by * 64, cb = bx * 64;
    int tr = threadIdx.x >> 6, tc = threadIdx.x & 63;
    const float* src = a.s[m];
    #pragma unroll
    for (int i = 0; i < 16; ++i) {
        int rr = tr + i * 4;
        tile[rr][tc] = src[(size_t)(rb + rr) * 512 + cb + tc];
    }
    __syncthreads();
    ushort_t* dst = a.d[m];
    int stride = a.stride[m], coff = a.coff[m];
    #pragma unroll
    for (int i = 0; i < 16; ++i) {
        int rr = tr + i * 4;
        dst[(size_t)(cb + rr) * stride + coff + rb + tc] = f2bf(tile[tc][rr]);
    }
}

// ---- biases + gate weight concat/transpose prep (grid 64x256 = 16384) ----
__global__ void prep(const float* bq, const float* bfp, const float* bk, const float* btp,
                     const float* bgF, const float* bgpF, const float* bgT, const float* bgpT,
                     const float* WgF, const float* WgpF, const float* WgT_, const float* WgpT,
                     float* bqf, float* bkt, float* bgFc, float* bgTc,
                     ushort_t* WgFT, ushort_t* WgTT) {
    int i = blockIdx.x * 256 + threadIdx.x;
    if (i < 512) { bqf[i] = bq[i] + bfp[i]; bkt[i] = bk[i] + btp[i]; }
    if (i < 8) { bgFc[i] = bgF[i] + bgpF[i] + 1.0f; bgTc[i] = bgT[i] + bgpT[i]; }
    int j = i >> 10, k = i & 1023;
    float vF = 0.f, vT = 0.f;
    if (j < 8) {
        vF = (k < 512) ? WgF[k * 8 + j] : WgpF[(k - 512) * 8 + j];
        vT = (k < 512) ? WgT_[k * 8 + j] : WgpT[(k - 512) * 8 + j];
    }
    WgFT[i] = f2bf(vF);
    WgTT[i] = f2bf(vT);
}

// ---- tiled bf16 GEMM: A=[A1|A2(mod)] [M,K] x WT[512][K] -> 128x128 tile, BK=64 ----
// LDS XOR-swizzle (elem col ^ (row&7)*8) via pre-swizzled global source.
// epi 0: Cb = bf16(acc + bias[c])
// epi 2: permuted-V layout
// epi 3: Cf = (f2 - mu)*rstd * (acc + bias[c] + 1)
__global__ __launch_bounds__(256, 2) void gemm_bf16(
    const ushort_t* __restrict__ A1, const ushort_t* __restrict__ A2, int rm, int K,
    const ushort_t* __restrict__ WT, const float* __restrict__ bias,
    float* __restrict__ Cf, ushort_t* __restrict__ Cb,
    const float* __restrict__ f2, const float* __restrict__ stats, int epi)
{
    __shared__ ushort_t As[128 * 64];
    __shared__ ushort_t Bs[128 * 64];
    int tid = threadIdx.x;
    int w = tid >> 6, l = tid & 63, fr = l & 15, g = l >> 4;
    int wr = w >> 1, wc = w & 1;
    int rb = blockIdx.x * 128, cb = blockIdx.y * 128;

    floatx4 acc[4][4];
    #pragma unroll
    for (int mt = 0; mt < 4; ++mt)
        #pragma unroll
        for (int nt = 0; nt < 4; ++nt)
            #pragma unroll
            for (int i = 0; i < 4; ++i) acc[mt][nt][i] = 0.f;

    int srow = w * 8 + (l >> 3);                 // 0..31
    int scx = ((l & 7) ^ (l >> 3)) * 8;          // swizzled k-offset 0..56

    for (int kb = 0; kb < K; kb += 64) {
        #pragma unroll
        for (int i = 0; i < 4; ++i) {
            int ra = rb + i * 32 + srow;
            int ka = kb + scx;
            const ushort_t* ga = (ka < 512) ? (A1 + (size_t)ra * 512 + ka)
                                            : (A2 + (size_t)(ra & rm) * 512 + (ka - 512));
            __builtin_amdgcn_global_load_lds((gconst_as*)ga, (lds_as*)(As + i * 2048 + w * 512), 16, 0, 0);
            const ushort_t* gb = WT + (size_t)(cb + i * 32 + srow) * K + kb + scx;
            __builtin_amdgcn_global_load_lds((gconst_as*)gb, (lds_as*)(Bs + i * 2048 + w * 512), 16, 0, 0);
        }
        __syncthreads();
        #pragma unroll
        for (int kk = 0; kk < 2; ++kk) {
            int co = (kk * 32 + g * 8) ^ ((fr & 7) * 8);
            short8 af[4], bw[4];
            #pragma unroll
            for (int mt = 0; mt < 4; ++mt)
                af[mt] = *(const short8*)&As[(wr * 64 + mt * 16 + fr) * 64 + co];
            #pragma unroll
            for (int nt = 0; nt < 4; ++nt)
                bw[nt] = *(const short8*)&Bs[(wc * 64 + nt * 16 + fr) * 64 + co];
            #pragma unroll
            for (int mt = 0; mt < 4; ++mt)
                #pragma unroll
                for (int nt = 0; nt < 4; ++nt)
                    acc[mt][nt] = __builtin_amdgcn_mfma_f32_16x16x32_bf16(af[mt], bw[nt], acc[mt][nt], 0, 0, 0);
        }
        __syncthreads();
    }

    #pragma unroll
    for (int mt = 0; mt < 4; ++mt) {
        #pragma unroll
        for (int nt = 0; nt < 4; ++nt) {
            #pragma unroll
            for (int i = 0; i < 4; ++i) {
                int r = rb + wr * 64 + mt * 16 + g * 4 + i;
                int c = cb + wc * 64 + nt * 16 + fr;
                float v = acc[mt][nt][i];
                if (epi == 0) {
                    Cb[(size_t)r * 512 + c] = f2bf(v + bias[c]);
                } else if (epi == 2) {
                    int bb = r >> 9, t = r & 511, hh = c >> 6, d = c & 63;
                    size_t idx = ((size_t)((bb * 8 + hh) * 64 + d)) * 512 +
                                 (t & ~31) + ((t >> 2) & 3) * 8 + ((t >> 4) & 1) * 4 + (t & 3);
                    Cb[idx] = f2bf(v + bias[c]);
                } else {
                    float mu = stats[r * 2], rs = stats[r * 2 + 1];
                    Cf[(size_t)r * 512 + c] = (f2[(size_t)r * 512 + c] - mu) * rs * (v + bias[c] + 1.0f);
                }
            }
        }
    }
}

// ---- gate via MFMA: sigmoid([X|P] @ WgT^T + bgc) ; N=16 tile (cols 8..15 zero) ----
// layout 0: G[((r>>12)*8+j)*4096 + (r&4095)]   (from-gate, head-major)
// layout 1: G[((r>>9)*8+j)*512 + (r&511)]      (to-gate, head-major)
__global__ __launch_bounds__(256) void gate_mfma(
    const ushort_t* __restrict__ A1, const ushort_t* __restrict__ A2, int rm,
    const ushort_t* __restrict__ WgT, const float* __restrict__ bgc,
    float* __restrict__ G, int layout)
{
    int tid = threadIdx.x, w = tid >> 6, l = tid & 63;
    int fr = l & 15, g = l >> 4;
    int rb = blockIdx.x * 64 + w * 16;
    int arow = rb + fr;
    floatx4 acc = {0.f, 0.f, 0.f, 0.f};
    #pragma unroll
    for (int ks = 0; ks < 32; ++ks) {
        int k0 = ks * 32 + g * 8;
        const ushort_t* ap = (k0 < 512) ? (A1 + (size_t)arow * 512 + k0)
                                        : (A2 + (size_t)(arow & rm) * 512 + (k0 - 512));
        short8 af = *(const short8*)ap;
        short8 bw = *(const short8*)(WgT + (size_t)fr * 1024 + k0);
        acc = __builtin_amdgcn_mfma_f32_16x16x32_bf16(af, bw, acc, 0, 0, 0);
    }
    if (fr < 8) {
        #pragma unroll
        for (int i = 0; i < 4; ++i) {
            int r = rb + g * 4 + i;
            float z = acc[i] + bgc[fr];
            float gv = 1.f / (1.f + __expf(-z));
            if (layout == 0) G[((size_t)((r >> 12) * 8 + fr)) * FLEN + (r & 4095)] = gv;
            else G[((size_t)((r >> 9) * 8 + fr)) * 512 + (r & 511)] = gv;
        }
    }
}

// ---- fused attention: swapped QK^T, P in registers, LDS-staged coalesced probs ----
__global__ __launch_bounds__(256, 2) void attn_kernel(
    const ushort_t* __restrict__ Q, const ushort_t* __restrict__ K,
    const ushort_t* __restrict__ Vp,
    const float* __restrict__ gFromT, const float* __restrict__ gToT,
    float* __restrict__ probs, ushort_t* __restrict__ ctrl)
{
    __shared__ float chunkbuf[4][16 * 132];   // per-wave staging (padded rows)
    int tid = threadIdx.x, w = tid >> 6, l = tid & 63;
    int fr = l & 15, g = l >> 4;
    int bh = blockIdx.y, b = bh >> 3, h = bh & 7;
    int fb = blockIdx.x * 64 + w * 16;
    int f = fb + fr;

    const ushort_t* qp = Q + ((size_t)(b * FLEN) + f) * 512 + h * 64 + g * 8;
    short8 qf0 = *(const short8*)qp;
    short8 qf1 = *(const short8*)(qp + 32);

    uint_t pbx[32], pby[32];
    float ssum = 0.f;
    const float* gtp = gToT + (size_t)bh * 512;

    #pragma unroll
    for (int tt = 0; tt < 32; ++tt) {
        const ushort_t* kp = K + ((size_t)(b * TLEN) + tt * 16 + fr) * 512 + h * 64 + g * 8;
        short8 kf0 = *(const short8*)kp;
        short8 kf1 = *(const short8*)(kp + 32);
        floatx4 sc = {0.f, 0.f, 0.f, 0.f};
        sc = __builtin_amdgcn_mfma_f32_16x16x32_bf16(kf0, qf0, sc, 0, 0, 0);  // C[t][f]
        sc = __builtin_amdgcn_mfma_f32_16x16x32_bf16(kf1, qf1, sc, 0, 0, 0);
        floatx4 gt = *(const floatx4*)(gtp + tt * 16 + g * 4);
        float e0 = __expf(sc[0] * 0.125f), e1 = __expf(sc[1] * 0.125f);
        float e2 = __expf(sc[2] * 0.125f), e3 = __expf(sc[3] * 0.125f);
        ssum += e0 + e1 + e2 + e3;
        float p0 = e0 * gt[0], p1 = e1 * gt[1], p2 = e2 * gt[2], p3 = e3 * gt[3];
        pbx[tt] = (uint_t)f2bf(p0) | ((uint_t)f2bf(p1) << 16);
        pby[tt] = (uint_t)f2bf(p2) | ((uint_t)f2bf(p3) << 16);
    }
    ssum += __shfl_xor(ssum, 16);
    ssum += __shfl_xor(ssum, 32);
    float fac = gFromT[(size_t)bh * FLEN + f] / ssum;

    // PV: control^T[d][f] = sum_t V^T[d][t] * P^T[t][f]
    floatx4 oacc[4];
    #pragma unroll
    for (int dt = 0; dt < 4; ++dt)
        #pragma unroll
        for (int i = 0; i < 4; ++i) oacc[dt][i] = 0.f;

    #pragma unroll
    for (int kt = 0; kt < 16; ++kt) {
        union { uint_t u[4]; short8 v; } bu;
        bu.u[0] = pbx[2 * kt];     bu.u[1] = pby[2 * kt];
        bu.u[2] = pbx[2 * kt + 1]; bu.u[3] = pby[2 * kt + 1];
        #pragma unroll
        for (int dt = 0; dt < 4; ++dt) {
            const ushort_t* vp = Vp + ((size_t)(bh * 64) + dt * 16 + fr) * 512 + kt * 32 + g * 8;
            short8 vf = *(const short8*)vp;
            oacc[dt] = __builtin_amdgcn_mfma_f32_16x16x32_bf16(vf, bu.v, oacc[dt], 0, 0, 0);
        }
    }

    // probs: per-wave LDS transpose; stores = two contiguous 512-B runs per instr
    float* cbuf = chunkbuf[w];
    int il2 = l >> 5, pos = l & 31;
    #pragma unroll
    for (int c = 0; c < 4; ++c) {
        #pragma unroll
        for (int t8 = 0; t8 < 8; ++t8) {
            int tt = c * 8 + t8;
            floatx4 pv;
            pv[0] = bf2f(pbx[tt] & 0xffffu) * fac;
            pv[1] = bf2f(pbx[tt] >> 16) * fac;
            pv[2] = bf2f(pby[tt] & 0xffffu) * fac;
            pv[3] = bf2f(pby[tt] >> 16) * fac;
            *(floatx4*)&cbuf[fr * 132 + t8 * 16 + g * 4] = pv;
        }
        #pragma unroll
        for (int rr = 0; rr < 8; ++rr) {
            int row = rr * 2 + il2;
            *(floatx4*)(probs + ((size_t)bh * FLEN + fb + row) * 512 + c * 128 + pos * 4)
                = *(const floatx4*)&cbuf[row * 132 + pos * 4];
        }
    }

    // control^T -> LDS (reuse chunk region) -> coalesced bf16 control rows
    ushort_t* ctile = (ushort_t*)cbuf;           // [16][72]
    #pragma unroll
    for (int dt = 0; dt < 4; ++dt)
        #pragma unroll
        for (int i = 0; i < 4; ++i)
            ctile[fr * 72 + dt * 16 + g * 4 + i] = f2bf(oacc[dt][i] * fac);

    int fl = l >> 2, dp = (l & 3) * 16;
    uint4 c0 = *(const uint4*)&ctile[fl * 72 + dp];
    uint4 c1 = *(const uint4*)&ctile[fl * 72 + dp + 8];
    ushort_t* cdst = ctrl + ((size_t)(b * FLEN) + fb + fl) * 512 + h * 64 + dp;
    *(uint4*)cdst = c0;
    *(uint4*)(cdst + 8) = c1;
}

extern "C" void kernel_launch(void* const* d_in, const int* in_sizes, int n_in,
                              void* d_out, int out_size, void* d_ws, size_t ws_size,
                              hipStream_t stream) {
    const float* from = (const float*)d_in[0];
    const float* to   = (const float*)d_in[1];
    const float* fpos = (const float*)d_in[2];
    const float* tpos = (const float*)d_in[3];
    const float* Wq  = (const float*)d_in[4];  const float* bq  = (const float*)d_in[5];
    const float* Wk  = (const float*)d_in[6];  const float* bk  = (const float*)d_in[7];
    const float* Wv  = (const float*)d_in[8];  const float* bv  = (const float*)d_in[9];
    const float* Wfp = (const float*)d_in[10]; const float* bfp = (const float*)d_in[11];
    const float* Wtp = (const float*)d_in[12]; const float* btp = (const float*)d_in[13];
    const float* Wg_to   = (const float*)d_in[14]; const float* bg_to   = (const float*)d_in[15];
    const float* Wgp_to  = (const float*)d_in[16]; const float* bgp_to  = (const float*)d_in[17];
    const float* Wg_from = (const float*)d_in[18]; const float* bg_from = (const float*)d_in[19];
    const float* Wgp_from= (const float*)d_in[20]; const float* bgp_from= (const float*)d_in[21];
    const float* Wm  = (const float*)d_in[22]; const float* bm  = (const float*)d_in[23];

    char* ws = (char*)d_ws;
    ushort_t* WqfT = (ushort_t*)ws; ws += 512 * 1024 * 2;
    ushort_t* WktT = (ushort_t*)ws; ws += 512 * 1024 * 2;
    ushort_t* WvT  = (ushort_t*)ws; ws += 512 * 512 * 2;
    ushort_t* WmT  = (ushort_t*)ws; ws += 512 * 512 * 2;
    ushort_t* WgFT = (ushort_t*)ws; ws += 16 * 1024 * 2;
    ushort_t* WgTT = (ushort_t*)ws; ws += 16 * 1024 * 2;
    float* bqf  = (float*)ws; ws += 512 * 4;
    float* bkt  = (float*)ws; ws += 512 * 4;
    float* bgFc = (float*)ws; ws += 64 * 4;
    float* bgTc = (float*)ws; ws += 64 * 4;
    ushort_t* fbf = (ushort_t*)ws; ws += (size_t)NB * FLEN * 512 * 2;
    ushort_t* tbf = (ushort_t*)ws; ws += (size_t)NB * TLEN * 512 * 2;
    ushort_t* Qbf = (ushort_t*)ws; ws += (size_t)NB * FLEN * 512 * 2;
    ushort_t* Kbf = (ushort_t*)ws; ws += (size_t)NB * TLEN * 512 * 2;
    ushort_t* Vp  = (ushort_t*)ws; ws += (size_t)NB * NH * 64 * 512 * 2;
    float* gFromT = (float*)ws; ws += (size_t)NB * NH * FLEN * 4;
    float* gToT   = (float*)ws; ws += (size_t)NB * NH * 512 * 4;
    ushort_t* ctrl = (ushort_t*)ws; ws += (size_t)NB * FLEN * 512 * 2;
    float* stats = (float*)ws; ws += (size_t)NB * FLEN * 2 * 4;
    if (ws_size < (size_t)(ws - (char*)d_ws)) return;
    // pos bf16 staging aliases ctrl (ctrl written only by attn, later)
    ushort_t* fposbf = ctrl;                       // 4096*512
    ushort_t* tposbf = ctrl + (size_t)FLEN * 512;  // 512*512

    conv_from_stats<<<NB * FLEN / 4, 256, 0, stream>>>(from, fbf, stats);
    conv3<<<1664, 256, 0, stream>>>(to, tbf, fpos, fposbf, tpos, tposbf);

    T6Args ta;
    ta.s[0] = Wq;  ta.d[0] = WqfT; ta.stride[0] = 1024; ta.coff[0] = 0;
    ta.s[1] = Wfp; ta.d[1] = WqfT; ta.stride[1] = 1024; ta.coff[1] = 512;
    ta.s[2] = Wk;  ta.d[2] = WktT; ta.stride[2] = 1024; ta.coff[2] = 0;
    ta.s[3] = Wtp; ta.d[3] = WktT; ta.stride[3] = 1024; ta.coff[3] = 512;
    ta.s[4] = Wv;  ta.d[4] = WvT;  ta.stride[4] = 512;  ta.coff[4] = 0;
    ta.s[5] = Wm;  ta.d[5] = WmT;  ta.stride[5] = 512;  ta.coff[5] = 0;
    transpose6<<<384, 256, 0, stream>>>(ta);

    prep<<<64, 256, 0, stream>>>(bq, bfp, bk, btp,
                                 bg_from, bgp_from, bg_to, bgp_to,
                                 Wg_from, Wgp_from, Wg_to, Wgp_to,
                                 bqf, bkt, bgFc, bgTc, WgFT, WgTT);

    // Q = [from|fpos] @ WqfT^T + bqf ; K = [to|tpos] @ WktT^T + bkt ; V = to @ WvT^T + bv (permuted)
    gemm_bf16<<<dim3(NB * FLEN / 128, 4), 256, 0, stream>>>(fbf, fposbf, FLEN - 1, 1024, WqfT, bqf, nullptr, Qbf, nullptr, nullptr, 0);
    gemm_bf16<<<dim3(NB * TLEN / 128, 4), 256, 0, stream>>>(tbf, tposbf, TLEN - 1, 1024, WktT, bkt, nullptr, Kbf, nullptr, nullptr, 0);
    gemm_bf16<<<dim3(NB * TLEN / 128, 4), 256, 0, stream>>>(tbf, tbf, TLEN - 1, 512, WvT, bv, nullptr, Vp, nullptr, nullptr, 2);

    gate_mfma<<<NB * FLEN / 64, 256, 0, stream>>>(fbf, fposbf, FLEN - 1, WgFT, bgFc, gFromT, 0);
    gate_mfma<<<NB * TLEN / 64, 256, 0, stream>>>(tbf, tposbf, TLEN - 1, WgTT, bgTc, gToT, 1);

    float* out = (float*)d_out;
    attn_kernel<<<dim3(FLEN / 64, NB * NH), 256, 0, stream>>>(Qbf, Kbf, Vp, gFromT, gToT,
                                                              out + (size_t)NB * FLEN * 512, ctrl);

    gemm_bf16<<<dim3(NB * FLEN / 128, 4), 256, 0, stream>>>(ctrl, ctrl, FLEN - 1, 512, WmT, bm, out, nullptr, from, stats, 3);
}